// Round 2
// baseline (3035.624 us; speedup 1.0000x reference)
//
#include <hip/hip_runtime.h>

#define NN 20000      // nodes
#define NE 160000     // edges per edge set
#define NL 20         // EGNN layer calls (4*DEPTH)

typedef float f32x4 __attribute__((ext_vector_type(4)));
typedef __bf16 bf16x8 __attribute__((ext_vector_type(8)));

__device__ __forceinline__ float silu_f(float v) {
  return v / (1.f + __expf(-v));
}

// ---------------------------------------------------------------------------
// Pack fp32 weight matrix [L][K][128] into MFMA-B-fragment order:
// out[((layer*ktn + kt)*8 + nt)*64 + lane][8], elem j = W[kt*32+(lane>>4)*8+j][nt*16+(lane&15)]
// ---------------------------------------------------------------------------
__global__ void pack_weights(const float* __restrict__ W, __bf16* __restrict__ out,
                             const int K, const int lstride, const int total) {
  const int idx = blockIdx.x * 256 + threadIdx.x;
  if (idx >= total) return;
  const int lane = idx & 63;
  const int nt = (idx >> 6) & 7;
  const int ktn = K >> 5;
  const int kt = (idx >> 9) % ktn;
  const int layer = (idx >> 9) / ktn;
  const int col = nt * 16 + (lane & 15);
  const int kb = kt * 32 + (lane >> 4) * 8;
  const float* src = W + (size_t)layer * lstride;
  __bf16* o = out + (size_t)idx * 8;
#pragma unroll
  for (int j = 0; j < 8; ++j) o[j] = (__bf16)src[(kb + j) * 128 + col];
}

// ---------------------------------------------------------------------------
__global__ void embed_kernel(const float* __restrict__ x, const float* __restrict__ embW,
                             const float* __restrict__ embB,
                             float* __restrict__ h, float* __restrict__ h0,
                             __bf16* __restrict__ hbf) {
  const int idx = blockIdx.x * 256 + threadIdx.x;   // grid sized exactly NN*128/256
  const int n = idx >> 7, d = idx & 127;
  const float v = x[n] * embW[d] + embB[d];
  h[idx] = v;
  h0[idx] = v;
  hbf[idx] = (__bf16)v;
}

// ---------------------------------------------------------------------------
// Wave-independent fused edge kernel: each wave owns 32 edges; no __syncthreads.
// A-fragments gathered straight from global hbf; LN is wave-local shfl reduce;
// T1 is wave-private swizzled LDS for the GEMM1->GEMM2 fragment transpose.
// ---------------------------------------------------------------------------
__global__ __launch_bounds__(256, 4) void edge_kernel(
    const __bf16* __restrict__ hbf, const float* __restrict__ pos,
    const int* __restrict__ ei, float* __restrict__ agg,
    const __bf16* __restrict__ w1p, const __bf16* __restrict__ w2p,
    const float* __restrict__ w1last,
    const float* __restrict__ bm1, const float* __restrict__ gm1, const float* __restrict__ sm1,
    const float* __restrict__ bm2, const float* __restrict__ gm2, const float* __restrict__ sm2) {
  __shared__ __bf16 T1s[4][32 * 128];   // 32 KB total, wave-private slices
  const int t = threadIdx.x, w = t >> 6, l = t & 63;
  const int lr = l & 15, lg = l >> 4;
  const int e0 = blockIdx.x * 128 + w * 32;
  char* T1 = (char*)T1s[w];

  // edge indices: lane owns edge lr (mt=0) and 16+lr (mt=1); "own" = edge l&31
  const int es0 = ei[e0 + lr],      ed0 = ei[NE + e0 + lr];
  const int es1 = ei[e0 + 16 + lr], ed1 = ei[NE + e0 + 16 + lr];
  const int hi = lg & 1;
  const int eso = hi ? es1 : es0;
  const int edo = hi ? ed1 : ed0;
  const float dx = pos[edo * 3 + 0] - pos[eso * 3 + 0];
  const float dy = pos[edo * 3 + 1] - pos[eso * 3 + 1];
  const float dz = pos[edo * 3 + 2] - pos[eso * 3 + 2];
  const float dist_own = sqrtf(dx * dx + dy * dy + dz * dz);

  // acc init = dist*Wm1[256] + bm1 ; C layout: row = mt*16 + lg*4 + r, col = nt*16 + lr
  f32x4 acc[2][8];
  {
    float drow[2][4];
#pragma unroll
    for (int mt = 0; mt < 2; ++mt)
#pragma unroll
      for (int r = 0; r < 4; ++r)
        drow[mt][r] = __shfl(dist_own, mt * 16 + lg * 4 + r);
#pragma unroll
    for (int nt = 0; nt < 8; ++nt) {
      const float wl = w1last[nt * 16 + lr], bb = bm1[nt * 16 + lr];
#pragma unroll
      for (int mt = 0; mt < 2; ++mt)
#pragma unroll
        for (int r = 0; r < 4; ++r)
          acc[mt][nt][r] = drow[mt][r] * wl + bb;
    }
  }
  // GEMM1: [32 x 256] @ [256 x 128], A gathered from global
#pragma unroll
  for (int kt = 0; kt < 8; ++kt) {
    const int koff = (kt & 3) * 32 + lg * 8;
    const int n0 = (kt < 4) ? ed0 : es0;
    const int n1 = (kt < 4) ? ed1 : es1;
    const bf16x8 a0 = *(const bf16x8*)(hbf + (size_t)n0 * 128 + koff);
    const bf16x8 a1 = *(const bf16x8*)(hbf + (size_t)n1 * 128 + koff);
#pragma unroll
    for (int nt = 0; nt < 8; ++nt) {
      const bf16x8 b = *(const bf16x8*)(w1p + ((size_t)((kt * 8 + nt) * 64 + l)) * 8);
      acc[0][nt] = __builtin_amdgcn_mfma_f32_16x16x32_bf16(a0, b, acc[0][nt], 0, 0, 0);
      acc[1][nt] = __builtin_amdgcn_mfma_f32_16x16x32_bf16(a1, b, acc[1][nt], 0, 0, 0);
    }
  }
  // LN1 + SiLU -> T1 (wave-local)
  {
    float g1c[8], s1c[8];
#pragma unroll
    for (int nt = 0; nt < 8; ++nt) { g1c[nt] = gm1[nt * 16 + lr]; s1c[nt] = sm1[nt * 16 + lr]; }
#pragma unroll
    for (int mt = 0; mt < 2; ++mt)
#pragma unroll
      for (int r = 0; r < 4; ++r) {
        float s = 0.f, q = 0.f;
#pragma unroll
        for (int nt = 0; nt < 8; ++nt) { const float v = acc[mt][nt][r]; s += v; q += v * v; }
#pragma unroll
        for (int m = 1; m < 16; m <<= 1) { s += __shfl_xor(s, m); q += __shfl_xor(q, m); }
        const float mu = s * 0.0078125f;
        const float rstd = rsqrtf(q * 0.0078125f - mu * mu + 1e-5f);
        const int row = mt * 16 + lg * 4 + r;
#pragma unroll
        for (int nt = 0; nt < 8; ++nt) {
          float v = (acc[mt][nt][r] - mu) * rstd * g1c[nt] + s1c[nt];
          v = silu_f(v);
          const int col = nt * 16 + lr;
          *(__bf16*)(T1 + ((row * 256 + col * 2) ^ ((row & 7) << 4))) = (__bf16)v;
        }
      }
  }
  // GEMM2: [32 x 128] @ [128 x 128]
  f32x4 acc2[2][8];
#pragma unroll
  for (int nt = 0; nt < 8; ++nt) {
    const float bb = bm2[nt * 16 + lr];
#pragma unroll
    for (int mt = 0; mt < 2; ++mt)
#pragma unroll
      for (int r = 0; r < 4; ++r) acc2[mt][nt][r] = bb;
  }
#pragma unroll
  for (int kt = 0; kt < 4; ++kt) {
    const bf16x8 a0 = *(const bf16x8*)(T1 + (((lr) * 256 + kt * 64 + lg * 16) ^ ((lr & 7) << 4)));
    const bf16x8 a1 = *(const bf16x8*)(T1 + (((16 + lr) * 256 + kt * 64 + lg * 16) ^ ((lr & 7) << 4)));
#pragma unroll
    for (int nt = 0; nt < 8; ++nt) {
      const bf16x8 b = *(const bf16x8*)(w2p + ((size_t)((kt * 8 + nt) * 64 + l)) * 8);
      acc2[0][nt] = __builtin_amdgcn_mfma_f32_16x16x32_bf16(a0, b, acc2[0][nt], 0, 0, 0);
      acc2[1][nt] = __builtin_amdgcn_mfma_f32_16x16x32_bf16(a1, b, acc2[1][nt], 0, 0, 0);
    }
  }
  // LN2 + SiLU + atomic scatter
  {
    float g2c[8], s2c[8];
#pragma unroll
    for (int nt = 0; nt < 8; ++nt) { g2c[nt] = gm2[nt * 16 + lr]; s2c[nt] = sm2[nt * 16 + lr]; }
#pragma unroll
    for (int mt = 0; mt < 2; ++mt)
#pragma unroll
      for (int r = 0; r < 4; ++r) {
        float s = 0.f, q = 0.f;
#pragma unroll
        for (int nt = 0; nt < 8; ++nt) { const float v = acc2[mt][nt][r]; s += v; q += v * v; }
#pragma unroll
        for (int m = 1; m < 16; m <<= 1) { s += __shfl_xor(s, m); q += __shfl_xor(q, m); }
        const float mu = s * 0.0078125f;
        const float rstd = rsqrtf(q * 0.0078125f - mu * mu + 1e-5f);
        const int row = mt * 16 + lg * 4 + r;
        const int dstn = __shfl(edo, row);
#pragma unroll
        for (int nt = 0; nt < 8; ++nt) {
          float v = (acc2[mt][nt][r] - mu) * rstd * g2c[nt] + s2c[nt];
          v = silu_f(v);
          atomicAdd(&agg[(size_t)dstn * 128 + nt * 16 + lr], v);
        }
      }
  }
}

// ---------------------------------------------------------------------------
// Wave-independent fused node-update kernel: 32 nodes/wave, no __syncthreads.
// Reads h (bf16 mirror) + agg (fp32, zeroed after read for the next round).
// mode==1 (r==3): add residual h0 and write new h0.
// ---------------------------------------------------------------------------
__global__ __launch_bounds__(256, 4) void update_kernel(
    float* __restrict__ h, float* __restrict__ aggv, __bf16* __restrict__ hbf,
    float* __restrict__ h0, const int mode,
    const __bf16* __restrict__ w1p, const __bf16* __restrict__ w2p,
    const float* __restrict__ bu1, const float* __restrict__ gu1, const float* __restrict__ su1,
    const float* __restrict__ bu2, const float* __restrict__ gu2, const float* __restrict__ su2) {
  __shared__ __bf16 T1s[4][32 * 128];
  const int t = threadIdx.x, w = t >> 6, l = t & 63;
  const int lr = l & 15, lg = l >> 4;
  const int n0 = blockIdx.x * 128 + w * 32;
  char* T1 = (char*)T1s[w];

  const int vA = (n0 + lr < NN), vB = (n0 + 16 + lr < NN);
  const int nA = vA ? (n0 + lr) : (NN - 1);
  const int nB = vB ? (n0 + 16 + lr) : (NN - 1);

  f32x4 acc[2][8];
#pragma unroll
  for (int nt = 0; nt < 8; ++nt) {
    const float bb = bu1[nt * 16 + lr];
#pragma unroll
    for (int mt = 0; mt < 2; ++mt)
#pragma unroll
      for (int r = 0; r < 4; ++r) acc[mt][nt][r] = bb;
  }
  // GEMM1: K = [h(128) | agg(128)]
#pragma unroll
  for (int kt = 0; kt < 8; ++kt) {
    bf16x8 a0, a1;
    if (kt < 4) {
      const int koff = kt * 32 + lg * 8;
      a0 = *(const bf16x8*)(hbf + (size_t)nA * 128 + koff);
      a1 = *(const bf16x8*)(hbf + (size_t)nB * 128 + koff);
    } else {
      const int koff = (kt - 4) * 32 + lg * 8;
      f32x4* pA = (f32x4*)(aggv + (size_t)nA * 128 + koff);
      f32x4* pB = (f32x4*)(aggv + (size_t)nB * 128 + koff);
      const f32x4 u0 = pA[0], u1 = pA[1];
      const f32x4 v0 = pB[0], v1 = pB[1];
#pragma unroll
      for (int j = 0; j < 4; ++j) {
        a0[j] = (__bf16)u0[j]; a0[j + 4] = (__bf16)u1[j];
        a1[j] = (__bf16)v0[j]; a1[j + 4] = (__bf16)v1[j];
      }
      // zero agg for the next round's atomics (only the owning lane)
      if (vA) { pA[0] = (f32x4)0.f; pA[1] = (f32x4)0.f; }
      if (vB) { pB[0] = (f32x4)0.f; pB[1] = (f32x4)0.f; }
    }
#pragma unroll
    for (int nt = 0; nt < 8; ++nt) {
      const bf16x8 b = *(const bf16x8*)(w1p + ((size_t)((kt * 8 + nt) * 64 + l)) * 8);
      acc[0][nt] = __builtin_amdgcn_mfma_f32_16x16x32_bf16(a0, b, acc[0][nt], 0, 0, 0);
      acc[1][nt] = __builtin_amdgcn_mfma_f32_16x16x32_bf16(a1, b, acc[1][nt], 0, 0, 0);
    }
  }
  // LN1 + SiLU -> T1
  {
    float g1c[8], s1c[8];
#pragma unroll
    for (int nt = 0; nt < 8; ++nt) { g1c[nt] = gu1[nt * 16 + lr]; s1c[nt] = su1[nt * 16 + lr]; }
#pragma unroll
    for (int mt = 0; mt < 2; ++mt)
#pragma unroll
      for (int r = 0; r < 4; ++r) {
        float s = 0.f, q = 0.f;
#pragma unroll
        for (int nt = 0; nt < 8; ++nt) { const float v = acc[mt][nt][r]; s += v; q += v * v; }
#pragma unroll
        for (int m = 1; m < 16; m <<= 1) { s += __shfl_xor(s, m); q += __shfl_xor(q, m); }
        const float mu = s * 0.0078125f;
        const float rstd = rsqrtf(q * 0.0078125f - mu * mu + 1e-5f);
        const int row = mt * 16 + lg * 4 + r;
#pragma unroll
        for (int nt = 0; nt < 8; ++nt) {
          float v = (acc[mt][nt][r] - mu) * rstd * g1c[nt] + s1c[nt];
          v = silu_f(v);
          const int col = nt * 16 + lr;
          *(__bf16*)(T1 + ((row * 256 + col * 2) ^ ((row & 7) << 4))) = (__bf16)v;
        }
      }
  }
  // GEMM2
  f32x4 acc2[2][8];
#pragma unroll
  for (int nt = 0; nt < 8; ++nt) {
    const float bb = bu2[nt * 16 + lr];
#pragma unroll
    for (int mt = 0; mt < 2; ++mt)
#pragma unroll
      for (int r = 0; r < 4; ++r) acc2[mt][nt][r] = bb;
  }
#pragma unroll
  for (int kt = 0; kt < 4; ++kt) {
    const bf16x8 a0 = *(const bf16x8*)(T1 + (((lr) * 256 + kt * 64 + lg * 16) ^ ((lr & 7) << 4)));
    const bf16x8 a1 = *(const bf16x8*)(T1 + (((16 + lr) * 256 + kt * 64 + lg * 16) ^ ((lr & 7) << 4)));
#pragma unroll
    for (int nt = 0; nt < 8; ++nt) {
      const bf16x8 b = *(const bf16x8*)(w2p + ((size_t)((kt * 8 + nt) * 64 + l)) * 8);
      acc2[0][nt] = __builtin_amdgcn_mfma_f32_16x16x32_bf16(a0, b, acc2[0][nt], 0, 0, 0);
      acc2[1][nt] = __builtin_amdgcn_mfma_f32_16x16x32_bf16(a1, b, acc2[1][nt], 0, 0, 0);
    }
  }
  // LN2 + SiLU + store h/hbf (+ residual, h0)
  {
    float g2c[8], s2c[8];
#pragma unroll
    for (int nt = 0; nt < 8; ++nt) { g2c[nt] = gu2[nt * 16 + lr]; s2c[nt] = su2[nt * 16 + lr]; }
#pragma unroll
    for (int mt = 0; mt < 2; ++mt)
#pragma unroll
      for (int r = 0; r < 4; ++r) {
        float s = 0.f, q = 0.f;
#pragma unroll
        for (int nt = 0; nt < 8; ++nt) { const float v = acc2[mt][nt][r]; s += v; q += v * v; }
#pragma unroll
        for (int m = 1; m < 16; m <<= 1) { s += __shfl_xor(s, m); q += __shfl_xor(q, m); }
        const float mu = s * 0.0078125f;
        const float rstd = rsqrtf(q * 0.0078125f - mu * mu + 1e-5f);
        const int row = mt * 16 + lg * 4 + r;
        const int n = n0 + row;
        if (n < NN) {
#pragma unroll
          for (int nt = 0; nt < 8; ++nt) {
            const int col = nt * 16 + lr;
            float v = (acc2[mt][nt][r] - mu) * rstd * g2c[nt] + s2c[nt];
            v = silu_f(v);
            if (mode) v += h0[(size_t)n * 128 + col];
            h[(size_t)n * 128 + col] = v;
            hbf[(size_t)n * 128 + col] = (__bf16)v;
            if (mode) h0[(size_t)n * 128 + col] = v;
          }
        }
      }
  }
}

// ---------------------------------------------------------------------------
__global__ void pool_kernel(const float* __restrict__ h, const int* __restrict__ bid,
                            float* __restrict__ pooled) {
  const int idx = blockIdx.x * 256 + threadIdx.x;   // grid sized exactly NN*128/256
  const int n = idx >> 7;
  atomicAdd(&pooled[bid[n] * 128 + (idx & 127)], h[idx]);
}

__global__ void head_kernel(const float* __restrict__ pooled,
                            const float* __restrict__ W1, const float* __restrict__ b1,
                            const float* __restrict__ W2, const float* __restrict__ b2,
                            float* __restrict__ out) {
  __shared__ float buf[2];
  const int b = blockIdx.x, t = threadIdx.x;
  float s = b1[t];
  for (int k = 0; k < 128; ++k) s += pooled[b * 128 + k] * W1[k * 128 + t];
  s = fmaxf(s, 0.f) * W2[t];
#pragma unroll
  for (int m = 32; m >= 1; m >>= 1) s += __shfl_down(s, m);
  if ((t & 63) == 0) buf[t >> 6] = s;
  __syncthreads();
  if (t == 0) out[b] = buf[0] + buf[1] + b2[0];
}

// ---------------------------------------------------------------------------
extern "C" void kernel_launch(void* const* d_in, const int* in_sizes, int n_in,
                              void* d_out, int out_size, void* d_ws, size_t ws_size,
                              hipStream_t stream) {
  const float* x   = (const float*)d_in[0];
  const float* pos = (const float*)d_in[1];
  const int* eis[4] = {(const int*)d_in[2], (const int*)d_in[3],
                       (const int*)d_in[4], (const int*)d_in[5]};
  const int* bid = (const int*)d_in[6];
  const float* embW = (const float*)d_in[7];
  const float* embB = (const float*)d_in[8];
  const float* Wm1 = (const float*)d_in[9];
  const float* bm1 = (const float*)d_in[10];
  const float* gm1 = (const float*)d_in[11];
  const float* sm1 = (const float*)d_in[12];
  const float* Wm2 = (const float*)d_in[13];
  const float* bm2 = (const float*)d_in[14];
  const float* gm2 = (const float*)d_in[15];
  const float* sm2 = (const float*)d_in[16];
  const float* Wu1 = (const float*)d_in[17];
  const float* bu1 = (const float*)d_in[18];
  const float* gu1 = (const float*)d_in[19];
  const float* su1 = (const float*)d_in[20];
  const float* Wu2 = (const float*)d_in[21];
  const float* bu2 = (const float*)d_in[22];
  const float* gu2 = (const float*)d_in[23];
  const float* su2 = (const float*)d_in[24];
  const float* pW1 = (const float*)d_in[25];
  const float* pb1 = (const float*)d_in[26];
  const float* pW2 = (const float*)d_in[27];
  const float* pb2 = (const float*)d_in[28];
  float* out = (float*)d_out;

  char* wp = (char*)d_ws;
  float* h = (float*)wp;      wp += (size_t)NN * 128 * 4;
  float* h0 = (float*)wp;     wp += (size_t)NN * 128 * 4;
  float* agg = (float*)wp;    wp += (size_t)NN * 128 * 4;
  float* pooled = (float*)wp; wp += 16 * 128 * 4;
  __bf16* hbf = (__bf16*)wp;  wp += (size_t)NN * 128 * 2;
  __bf16* w1p = (__bf16*)wp;  wp += (size_t)NL * 32768 * 2;  // Wm1 (K=256 part), packed
  __bf16* w2p = (__bf16*)wp;  wp += (size_t)NL * 16384 * 2;  // Wm2
  __bf16* wu1p = (__bf16*)wp; wp += (size_t)NL * 32768 * 2;  // Wu1
  __bf16* wu2p = (__bf16*)wp; wp += (size_t)NL * 16384 * 2;  // Wu2

  pack_weights<<<320, 256, 0, stream>>>(Wm1, w1p, 256, 257 * 128, NL * 8 * 8 * 64);
  pack_weights<<<160, 256, 0, stream>>>(Wm2, w2p, 128, 128 * 128, NL * 4 * 8 * 64);
  pack_weights<<<320, 256, 0, stream>>>(Wu1, wu1p, 256, 256 * 128, NL * 8 * 8 * 64);
  pack_weights<<<160, 256, 0, stream>>>(Wu2, wu2p, 128, 128 * 128, NL * 4 * 8 * 64);

  // agg must be zero before the first edge round; update_kernel re-zeroes it
  // after consuming it each round, so one memset per call suffices.
  hipMemsetAsync(agg, 0, (size_t)NN * 128 * 4, stream);
  embed_kernel<<<(NN * 128) / 256, 256, 0, stream>>>(x, embW, embB, h, h0, hbf);

  for (int layer = 0; layer < 5; ++layer) {
    for (int r = 0; r < 4; ++r) {
      const int i = layer * 4 + r;
      edge_kernel<<<NE / 128, 256, 0, stream>>>(
          hbf, pos, eis[r], agg,
          w1p + (size_t)i * 32768, w2p + (size_t)i * 16384,
          Wm1 + (size_t)i * 257 * 128 + 256 * 128,
          bm1 + i * 128, gm1 + i * 128, sm1 + i * 128,
          bm2 + i * 128, gm2 + i * 128, sm2 + i * 128);
      update_kernel<<<(NN + 127) / 128, 256, 0, stream>>>(
          h, agg, hbf, h0, (r == 3) ? 1 : 0,
          wu1p + (size_t)i * 32768, wu2p + (size_t)i * 16384,
          bu1 + i * 128, gu1 + i * 128, su1 + i * 128,
          bu2 + i * 128, gu2 + i * 128, su2 + i * 128);
    }
  }

  hipMemsetAsync(pooled, 0, 16 * 128 * 4, stream);
  pool_kernel<<<(NN * 128) / 256, 256, 0, stream>>>(h, bid, pooled);
  head_kernel<<<16, 128, 0, stream>>>(pooled, pW1, pb1, pW2, pb2, out);
}